// Round 6
// baseline (9300.011 us; speedup 1.0000x reference)
//
#include <hip/hip_runtime.h>

typedef unsigned short u16;
typedef __attribute__((ext_vector_type(8))) short bf16x8;
typedef __attribute__((ext_vector_type(4))) float f32x4;

#define NB 128
#define NOBJ 36
#define VDIM 2048
#define EMB 1024
#define HID 1024
#define NTOK 10000
#define MAXLEN 20
#define T_STEPS 19
#define PRED_STRIDE (MAXLEN * NTOK)          /* 200000 */
#define ALPHA_OFF ((long)NB * MAXLEN * NTOK) /* 25,600,000 */
#define HSZ (NB * HID)                       /* 131072 */
#define BAR_GEN (512 * 16)
#define BAR_BYTES ((512 * 16 + 16) * 4)

struct Args {
  const float *v, *caption;
  const int *cap_len;
  const float *Wih1, *Whh1, *bih1, *bhh1, *Wih2, *Whh2, *bih2, *bhh2;
  const float *Wv, *bv, *Wq, *bq, *wa, *ba, *W1, *b1, *W2, *b2;
  float *out;
  unsigned *bar;
  int *order, *dl;
  u16 *Wvh, *vh, *Wqh, *Wql, *W1T, *Wih2c, *Wih2hql, *vproj16;
  // fragment-packed GEMM operands: [colgrp][K/32][64 lanes][8]
  u16 *W1aP, *W1vP, *W1cP, *Whh1P, *Whh2P, *Wih2aP, *W2P, *Wq1P, *Wih2qP;
  u16 *capphp, *capplp;
  u16 *h1hp, *h1lp, *h2hp, *h2lp, *avhp, *avlp, *vmhp, *vmlp;
  float *gv1, *gh2s, *h1f, *h2f, *gcap, *g1c, *gi2h1, *qf;
  float *bq1f, *bf2f;
};

__device__ inline float b2f(u16 h) {
  unsigned u = ((unsigned)h) << 16;
  float f;
  __builtin_memcpy(&f, &u, 4);
  return f;
}
__device__ inline u16 f2b_trunc(float x) {
  unsigned u;
  __builtin_memcpy(&u, &x, 4);
  return (u16)(u >> 16);
}
__device__ inline u16 f2b_rne(float x) {
  unsigned u;
  __builtin_memcpy(&u, &x, 4);
  unsigned r = (u + 0x7fffu + ((u >> 16) & 1u)) >> 16;
  return (u16)r;
}
__device__ inline void split_bf16(float x, u16 &hi, u16 &lo) {
  hi = f2b_trunc(x);
  lo = f2b_trunc(x - b2f(hi));
}
__device__ inline bf16x8 ldb8(const u16 *p) {
  uint4 u = *(const uint4 *)p;
  bf16x8 v;
  __builtin_memcpy(&v, &u, 16);
  return v;
}
__device__ inline f32x4 mfma16(bf16x8 a, bf16x8 b, f32x4 c) {
  return __builtin_amdgcn_mfma_f32_16x16x32_bf16(a, b, c, 0, 0, 0);
}
__device__ inline float sigmoidf_(float x) {
  float e = __expf(-fabsf(x));
  float p = 1.f / (1.f + e);
  return x >= 0.f ? p : 1.f - p;
}
__device__ inline float tanhf_(float x) {
  float e = __expf(-2.f * fabsf(x));
  float t = (1.f - e) / (1.f + e);
  return x >= 0.f ? t : -t;
}
__device__ inline float wred_sum(float x) {
#pragma unroll
  for (int off = 32; off > 0; off >>= 1) x += __shfl_xor(x, off, 64);
  return x;
}
__device__ inline float wred_max(float x) {
#pragma unroll
  for (int off = 32; off > 0; off >>= 1) x = fmaxf(x, __shfl_xor(x, off, 64));
  return x;
}
__device__ inline void ntstf(float *p, float v) {
  __builtin_nontemporal_store(v, p);
}
__device__ inline f32x4 ntld4(const float *p) {
  return __builtin_nontemporal_load((const f32x4 *)p);
}

// store-arrival barrier: relaxed polls only (no per-poll cache invalidation);
// one __threadfence (release) before arrival, one (acquire) after release.
__device__ inline void gbar(unsigned *bar, int blk, int gx, unsigned target) {
  __syncthreads();
  __threadfence();
  if (threadIdx.x == 0)
    __hip_atomic_store(&bar[blk * 16], target, __ATOMIC_RELAXED,
                       __HIP_MEMORY_SCOPE_AGENT);
  if (blk == 0) {
    for (int s = threadIdx.x; s < gx; s += 512) {
      while (__hip_atomic_load(&bar[s * 16], __ATOMIC_RELAXED,
                               __HIP_MEMORY_SCOPE_AGENT) < target)
        __builtin_amdgcn_s_sleep(2);
    }
    __syncthreads();
    if (threadIdx.x == 0) {
      __threadfence();
      __hip_atomic_store(&bar[BAR_GEN], target, __ATOMIC_RELAXED,
                         __HIP_MEMORY_SCOPE_AGENT);
    }
  } else if (threadIdx.x == 0) {
    while (__hip_atomic_load(&bar[BAR_GEN], __ATOMIC_RELAXED,
                             __HIP_MEMORY_SCOPE_AGENT) < target)
      __builtin_amdgcn_s_sleep(2);
  }
  __syncthreads();
  __threadfence();
}

// f32 -> bf16(RNE), grid-strided, NT loads (one-shot data)
__device__ inline void cvt_hi(const float *src, u16 *dst, long n, long g0,
                              long gs) {
  for (long i = g0 * 4; i < n; i += gs * 4) {
    f32x4 f = ntld4(src + i);
    ushort4 o;
    o.x = f2b_rne(f[0]);
    o.y = f2b_rne(f[1]);
    o.z = f2b_rne(f[2]);
    o.w = f2b_rne(f[3]);
    *(ushort4 *)(dst + i) = o;
  }
}
__device__ inline void cvt_split(const float *src, u16 *dhi, u16 *dlo, long n,
                                 long g0, long gs) {
  for (long i = g0 * 4; i < n; i += gs * 4) {
    f32x4 f = ntld4(src + i);
    ushort4 h, l;
    split_bf16(f[0], h.x, l.x);
    split_bf16(f[1], h.y, l.y);
    split_bf16(f[2], h.z, l.z);
    split_bf16(f[3], h.w, l.w);
    *(ushort4 *)(dhi + i) = h;
    *(ushort4 *)(dlo + i) = l;
  }
}

// pack W[O][Ksrc] (f32, RNE) window [k0, k0+K) into fragment-major layout
__device__ inline void packW(const float *src, u16 *dst, int O, int K, int Ksrc,
                             int k0, long g0, long gs) {
  const int kblk = K >> 5;
  const long nfrag = (long)(O >> 4) * kblk * 64;
  for (long f = g0; f < nfrag; f += gs) {
    const int lane_ = (int)(f & 63);
    const long cgks = f >> 6;
    const int ks = (int)(cgks % kblk);
    const int colg = (int)(cgks / kblk);
    const int col = colg * 16 + (lane_ & 15);
    const int k = k0 + ks * 32 + (lane_ >> 4) * 8;
    const float *s = src + (long)col * Ksrc + k;
    f32x4 f0 = ntld4(s), f1 = ntld4(s + 4);
    ushort4 o0, o1;
    o0.x = f2b_rne(f0[0]);
    o0.y = f2b_rne(f0[1]);
    o0.z = f2b_rne(f0[2]);
    o0.w = f2b_rne(f0[3]);
    o1.x = f2b_rne(f1[0]);
    o1.y = f2b_rne(f1[1]);
    o1.z = f2b_rne(f1[2]);
    o1.w = f2b_rne(f1[3]);
    *(ushort4 *)(dst + f * 8) = o0;
    *(ushort4 *)(dst + f * 8 + 4) = o1;
  }
}

// ---------------- linear-layout GEMM helpers (one-shot phases only) --------
#define MMK_BODY                                                               \
  {                                                                            \
    const int ko = ks * 32;                                                    \
    bf16x8 va = ldb8(ah + ko);                                                 \
    bf16x8 vl;                                                                 \
    if constexpr (SPLIT) vl = ldb8(al + ko);                                   \
    _Pragma("unroll") for (int i = 0; i < NT; ++i) {                           \
      bf16x8 vb = ldb8(wr + (long)i * wstride + ko);                           \
      acc[i] = mfma16(va, vb, acc[i]);                                         \
      if constexpr (SPLIT) acc[i] = mfma16(vl, vb, acc[i]);                    \
    }                                                                          \
  }

template <int NT, bool SPLIT>
__device__ inline void mmk(f32x4 *acc, const u16 *ah, const u16 *al,
                           const u16 *wr, long wstride, int ksteps) {
#pragma unroll 2
  for (int ks = 0; ks < ksteps; ++ks) MMK_BODY
}

template <bool SPLIT>
__device__ inline f32x4 tile16(const u16 *ah, const u16 *al, const u16 *wr,
                               int K) {
  f32x4 acch = {0.f, 0.f, 0.f, 0.f};
  f32x4 accl = {0.f, 0.f, 0.f, 0.f};
  const int ksteps = K >> 5;
#pragma unroll 4
  for (int ks = 0; ks < ksteps; ++ks) {
    const int ko = ks * 32;
    bf16x8 vb = ldb8(wr + ko);
    acch = mfma16(ldb8(ah + ko), vb, acch);
    if constexpr (SPLIT) accl = mfma16(ldb8(al + ko), vb, accl);
  }
  if constexpr (SPLIT) {
#pragma unroll
    for (int r = 0; r < 4; ++r) acch[r] += accl[r];
  }
  return acch;
}

// packed GEMM: pointers pre-offset to (tile, lane); every load = 1KB/wave.
template <bool SPLIT>
__device__ inline f32x4 tile16p(const u16 *ah, const u16 *al, const u16 *bp,
                                int ksteps) {
  f32x4 acch = {0.f, 0.f, 0.f, 0.f};
  f32x4 accl = {0.f, 0.f, 0.f, 0.f};
#pragma unroll 4
  for (int ks = 0; ks < ksteps; ++ks) {
    bf16x8 vb = ldb8(bp + ks * 512);
    acch = mfma16(ldb8(ah + ks * 512), vb, acch);
    if constexpr (SPLIT) accl = mfma16(ldb8(al + ks * 512), vb, accl);
  }
  if constexpr (SPLIT) {
#pragma unroll
    for (int r = 0; r < 4; ++r) acch[r] += accl[r];
  }
  return acch;
}

// 3-gate packed GEMM: shared split-A, 3 B tiles (for fused GRU phases)
template <int KSTEPS>
__device__ inline void tile3(f32x4 acc[3], const u16 *ah, const u16 *al,
                             const u16 *b0, const u16 *b1, const u16 *b2) {
#pragma unroll 2
  for (int ks = 0; ks < KSTEPS; ++ks) {
    bf16x8 va = ldb8(ah + ks * 512);
    bf16x8 vl = ldb8(al + ks * 512);
    bf16x8 w0 = ldb8(b0 + ks * 512);
    bf16x8 w1 = ldb8(b1 + ks * 512);
    bf16x8 w2 = ldb8(b2 + ks * 512);
    acc[0] = mfma16(va, w0, acc[0]);
    acc[1] = mfma16(va, w1, acc[1]);
    acc[2] = mfma16(va, w2, acc[2]);
    acc[0] = mfma16(vl, w0, acc[0]);
    acc[1] = mfma16(vl, w1, acc[1]);
    acc[2] = mfma16(vl, w2, acc[2]);
  }
}

__global__ void __launch_bounds__(512, 4) butd(Args a) {
  const int tid = threadIdx.x;
  const int blk = blockIdx.x;
  const int gx = gridDim.x;
  const int lane = tid & 63;
  const int wv = tid >> 6;
  const int m = lane & 15;
  const int quad = lane >> 4;
  __shared__ float sl[64];

  const long gs = (long)gx * 512;
  const long g0 = (long)blk * 512 + tid;
  unsigned bgen = 1;
  auto GB = [&]() { gbar(a.bar, blk, gx, bgen++); };

  //================= P0: pack/convert weights + argsort + zero-init =========
  packW(a.Wih1, a.W1aP, 3072, 1024, 4096, 0, g0, gs);
  packW(a.Wih1, a.W1vP, 3072, 2048, 4096, 1024, g0, gs);
  packW(a.Wih1, a.W1cP, 3072, 1024, 4096, 3072, g0, gs);
  packW(a.Whh1, a.Whh1P, 3072, 1024, 1024, 0, g0, gs);
  packW(a.Whh2, a.Whh2P, 3072, 1024, 1024, 0, g0, gs);
  packW(a.Wih2, a.Wih2aP, 3072, 2048, 3072, 0, g0, gs);
  packW(a.W2, a.W2P, NTOK, 1024, 1024, 0, g0, gs);
  cvt_hi(a.Wv, a.Wvh, 1024L * 2048, g0, gs);
  cvt_hi(a.v, a.vh, (long)NB * NOBJ * VDIM, g0, gs);
  cvt_split(a.Wq, a.Wqh, a.Wql, 1024L * 1024, g0, gs);
  for (long i = g0; i < 1024L * 1024; i += gs) {
    const int ii = (int)(i >> 10), mm2 = (int)(i & 1023);
    a.W1T[i] = f2b_rne(a.W1[(long)mm2 * 1024 + ii]);
  }
  for (long i = g0 * 4; i < 3072L * 1024; i += gs * 4) {
    const int row = (int)(i >> 10), c = (int)(i & 1023);
    f32x4 f = ntld4(a.Wih2 + (long)row * 3072 + 2048 + c);
    ushort4 h, l;
    h.x = f2b_rne(f[0]);
    h.y = f2b_rne(f[1]);
    h.z = f2b_rne(f[2]);
    h.w = f2b_rne(f[3]);
    l.x = f2b_trunc(f[0] - b2f(h.x));
    l.y = f2b_trunc(f[1] - b2f(h.y));
    l.z = f2b_trunc(f[2] - b2f(h.z));
    l.w = f2b_trunc(f[3] - b2f(h.w));
    *(ushort4 *)(a.Wih2c + i) = h;
    *(ushort4 *)(a.Wih2hql + i) = l;
  }

  if (blk == 0 && tid < NB) {
    int ki = a.cap_len[tid];
    int rank = 0;
    for (int j = 0; j < NB; ++j) {
      int kj = a.cap_len[j];
      rank += (kj > ki) || (kj == ki && j < tid);
    }
    a.order[rank] = tid;
    a.dl[rank] = ki - 1;
  }
  for (long i = g0; i < (long)NB * NTOK; i += gs) {
    long b = i / NTOK, n = i - b * NTOK;
    ntstf(&a.out[b * PRED_STRIDE + (long)(MAXLEN - 1) * NTOK + n], 0.f);
  }
  for (long i = g0; i < (long)NB * NOBJ; i += gs) {
    long b = i / NOBJ, n = i - b * NOBJ;
    ntstf(&a.out[ALPHA_OFF + b * (MAXLEN * NOBJ) + (MAXLEN - 1) * NOBJ + n],
          0.f);
  }
  for (long i = g0; i < HSZ; i += gs) {
    a.h1f[i] = 0.f;
    a.h2f[i] = 0.f;
    a.h1hp[i] = 0;
    a.h1lp[i] = 0;
    a.h2hp[i] = 0;
    a.h2lp[i] = 0;
  }
  for (long i = g0; i < 128L * 3072; i += gs) a.g1c[i] = 0.f;
  GB();

  //================= P1: v_mean(packed) + caption pack + vproj + bias folds =
  for (int b = blk; b < NB; b += gx) {
    const int ob = a.order[b];
    if (tid < 256) {
      const int d0 = tid * 8;
      const float *vb = a.v + (long)ob * NOBJ * VDIM + d0;
      float s[8] = {};
      for (int k = 0; k < NOBJ; ++k) {
        f32x4 x0 = *(const f32x4 *)(vb + (long)k * VDIM);
        f32x4 x1 = *(const f32x4 *)(vb + (long)k * VDIM + 4);
#pragma unroll
        for (int j = 0; j < 4; ++j) {
          s[j] += x0[j];
          s[4 + j] += x1[j];
        }
      }
#pragma unroll
      for (int j = 0; j < 8; ++j) s[j] *= (1.f / 36.f);
      ushort4 H0, H1, L0, L1;
      split_bf16(s[0], H0.x, L0.x);
      split_bf16(s[1], H0.y, L0.y);
      split_bf16(s[2], H0.z, L0.z);
      split_bf16(s[3], H0.w, L0.w);
      split_bf16(s[4], H1.x, L1.x);
      split_bf16(s[5], H1.y, L1.y);
      split_bf16(s[6], H1.z, L1.z);
      split_bf16(s[7], H1.w, L1.w);
      const long po = (((long)(b >> 4) * 64 + (d0 >> 5)) * 64 +
                       ((d0 >> 3) & 3) * 16 + (b & 15)) *
                      8;
      *(ushort4 *)(a.vmhp + po) = H0;
      *(ushort4 *)(a.vmhp + po + 4) = H1;
      *(ushort4 *)(a.vmlp + po) = L0;
      *(ushort4 *)(a.vmlp + po + 4) = L1;
    }
  }
  for (long f = g0; f < 19L * 8 * 32 * 64; f += gs) {
    const int lane_ = (int)(f & 63);
    long rest = f >> 6;
    const int ks = (int)(rest & 31);
    rest >>= 5;
    const int tile = (int)(rest & 7);
    const int t = (int)(rest >> 3);
    const int b = a.order[tile * 16 + (lane_ & 15)];
    const int k = ks * 32 + (lane_ >> 4) * 8;
    const float *s = a.caption + ((long)b * MAXLEN + t) * EMB + k;
    f32x4 f0 = ntld4(s), f1 = ntld4(s + 4);
    ushort4 H0, H1, L0, L1;
    split_bf16(f0[0], H0.x, L0.x);
    split_bf16(f0[1], H0.y, L0.y);
    split_bf16(f0[2], H0.z, L0.z);
    split_bf16(f0[3], H0.w, L0.w);
    split_bf16(f1[0], H1.x, L1.x);
    split_bf16(f1[1], H1.y, L1.y);
    split_bf16(f1[2], H1.z, L1.z);
    split_bf16(f1[3], H1.w, L1.w);
    *(ushort4 *)(a.capphp + f * 8) = H0;
    *(ushort4 *)(a.capphp + f * 8 + 4) = H1;
    *(ushort4 *)(a.capplp + f * 8) = L0;
    *(ushort4 *)(a.capplp + f * 8 + 4) = L1;
  }
  for (int tt = blk; tt < 576; tt += gx) {
    const int mg = tt % 36, ngr = tt / 36;
    const int row = mg * 128 + wv * 16 + m;
    const int bb = row / NOBJ, ko = row - bb * NOBJ;
    const u16 *ar = a.vh + ((long)a.order[bb] * NOBJ + ko) * VDIM + quad * 8;
    const int c0 = ngr * 64;
    const u16 *wr = a.Wvh + (long)(c0 + m) * VDIM + quad * 8;
    f32x4 acc[4] = {};
    mmk<4, false>(acc, ar, nullptr, wr, 16L * VDIM, VDIM / 32);
#pragma unroll
    for (int i = 0; i < 4; ++i) {
      const int col = c0 + i * 16 + m;
      const float bvv = a.bv[col];
#pragma unroll
      for (int r = 0; r < 4; ++r) {
        const int grow = mg * 128 + wv * 16 + quad * 4 + r;
        a.vproj16[(long)grow * HID + col] = f2b_rne(fmaxf(acc[i][r] + bvv, 0.f));
      }
    }
  }
  for (int o = blk * 8 + wv; o < 4096; o += gx * 8) {
    if (o < 1024) {
      float s = 0.f;
      for (int c = lane; c < 1024; c += 64) s += a.Wq[(long)o * 1024 + c] * a.b1[c];
      s = wred_sum(s);
      if (lane == 0) a.bq1f[o] = s + a.bq[o];
    } else {
      const int oo = o - 1024;
      float s = 0.f;
      for (int c = lane; c < 1024; c += 64)
        s += a.Wih2[(long)oo * 3072 + 2048 + c] * a.b1[c];
      s = wred_sum(s);
      if (lane == 0) a.bf2f[oo] = s;
    }
  }
  GB();

  //== P2: gv1, gcap (all t), fold GEMMs (outputs packed) ====================
  for (int task = blk; task < 5888; task += gx) {
    if (task < 192) {
      const u16 *ah = a.vmhp + (long)wv * 64 * 512 + lane * 8;
      const u16 *al = a.vmlp + (long)wv * 64 * 512 + lane * 8;
      f32x4 acc = tile16p<true>(ah, al,
                                a.W1vP + (long)task * 64 * 512 + lane * 8, 64);
      const int col = task * 16 + m;
      const float bb = a.bih1[col];
#pragma unroll
      for (int r = 0; r < 4; ++r)
        a.gv1[(long)(wv * 16 + quad * 4 + r) * 3072 + col] = acc[r] + bb;
    } else if (task < 3840) {
      const int tt2 = task - 192;
      const int tdx = tt2 / 192, ct = tt2 % 192;
      const u16 *ah = a.capphp + ((long)(tdx * 8 + wv) * 32) * 512 + lane * 8;
      const u16 *al = a.capplp + ((long)(tdx * 8 + wv) * 32) * 512 + lane * 8;
      f32x4 acc =
          tile16p<true>(ah, al, a.W1cP + (long)ct * 32 * 512 + lane * 8, 32);
      const int col = ct * 16 + m;
#pragma unroll
      for (int r = 0; r < 4; ++r)
        a.gcap[((long)tdx * NB + wv * 16 + quad * 4 + r) * 3072 + col] = acc[r];
    } else if (task < 4352) {
      const int tt2 = task - 3840;
      const int rg = tt2 >> 6, ct = tt2 & 63;
      const int row = rg * 128 + wv * 16 + m, col = ct * 16 + m;
      f32x4 acc = tile16<true>(a.Wqh + (long)row * HID + quad * 8,
                               a.Wql + (long)row * HID + quad * 8,
                               a.W1T + (long)col * HID + quad * 8, HID);
#pragma unroll
      for (int r = 0; r < 4; ++r) {
        const int n = rg * 128 + wv * 16 + quad * 4 + r;
        a.Wq1P[((long)(n >> 4) * 32 + (col >> 5)) * 512 +
               (((col >> 3) & 3) * 16 + (n & 15)) * 8 + (col & 7)] =
            f2b_rne(acc[r]);
      }
    } else {
      const int tt2 = task - 4352;
      const int rg = tt2 >> 6, ct = tt2 & 63;
      const int row = rg * 128 + wv * 16 + m, col = ct * 16 + m;
      f32x4 acc = tile16<true>(a.Wih2c + (long)row * 1024 + quad * 8,
                               a.Wih2hql + (long)row * 1024 + quad * 8,
                               a.W1T + (long)col * HID + quad * 8, HID);
#pragma unroll
      for (int r = 0; r < 4; ++r) {
        const int n = rg * 128 + wv * 16 + quad * 4 + r;
        a.Wih2qP[((long)(n >> 4) * 32 + (col >> 5)) * 512 +
                 (((col >> 3) & 3) * 16 + (n & 15)) * 8 + (col & 7)] =
            f2b_rne(acc[r]);
      }
    }
  }
  GB();

  //================= steady-state lambdas ===================================
  auto word_tile = [&](int wt, int tf, int pb) {
    const long ab = ((long)(pb * 8 + wv) * 32) * 512 + lane * 8;
    f32x4 acc = tile16p<true>(a.h2hp + ab, a.h2lp + ab,
                              a.W2P + (long)wt * 32 * 512 + lane * 8, 32);
    const int col = wt * 16 + m;
    const float bb = a.b2[col];
#pragma unroll
    for (int r = 0; r < 4; ++r) {
      const int grow = wv * 16 + quad * 4 + r;
      const int msk = tf < a.dl[grow];
      ntstf(&a.out[(long)grow * PRED_STRIDE + (long)tf * NTOK + col],
            msk ? acc[r] + bb : 0.f);
    }
  };

  auto attention = [&](int t, int b, int half) {
    __syncthreads();
    const int ob = a.order[b];
    const float *qrow = a.qf + (long)b * HID;
    for (int k = wv; k < NOBJ; k += 8) {
      const u16 *vp = a.vproj16 + ((long)b * NOBJ + k) * HID;
      float s = 0.f;
      for (int d = lane; d < HID; d += 64) s += b2f(vp[d]) * qrow[d] * a.wa[d];
      s = wred_sum(s);
      if (lane == 0) sl[k] = s + a.ba[0];
    }
    __syncthreads();
    if (wv == 0) {
      float x = (lane < NOBJ) ? sl[lane] : -3.0e38f;
      float mx = wred_max(x);
      float e = (lane < NOBJ) ? __expf(x - mx) : 0.f;
      float den = wred_sum(e);
      float att = e / den;
      if (lane < NOBJ) {
        sl[lane] = att;
        if (half == 0) {
          const int msk = t < a.dl[b];
          ntstf(&a.out[ALPHA_OFF + (long)b * (MAXLEN * NOBJ) + t * NOBJ + lane],
                msk ? att : 0.f);
        }
      }
    }
    __syncthreads();
    if (tid < 128) {
      const int d0 = half * 1024 + tid * 8;
      const u16 *vb = a.vh + (long)ob * NOBJ * VDIM + d0;
      float s[8] = {};
      for (int k = 0; k < NOBJ; ++k) {
        bf16x8 vv = ldb8(vb + (long)k * VDIM);
        const float w = sl[k];
#pragma unroll
        for (int j = 0; j < 8; ++j) s[j] += w * b2f((u16)vv[j]);
      }
      ushort4 H0, H1, L0, L1;
      split_bf16(s[0], H0.x, L0.x);
      split_bf16(s[1], H0.y, L0.y);
      split_bf16(s[2], H0.z, L0.z);
      split_bf16(s[3], H0.w, L0.w);
      split_bf16(s[4], H1.x, L1.x);
      split_bf16(s[5], H1.y, L1.y);
      split_bf16(s[6], H1.z, L1.z);
      split_bf16(s[7], H1.w, L1.w);
      const long po = (((long)(b >> 4) * 64 + (d0 >> 5)) * 64 +
                       ((d0 >> 3) & 3) * 16 + (b & 15)) *
                      8;
      *(ushort4 *)(a.avhp + po) = H0;
      *(ushort4 *)(a.avhp + po + 4) = H1;
      *(ushort4 *)(a.avlp + po) = L0;
      *(ushort4 *)(a.avlp + po + 4) = L1;
    }
  };

  //================= time loop: 4 fused phases per step =====================
  for (int t = 0; t < T_STEPS; ++t) {
    const int pr = t & 1, pw = pr ^ 1;

    // Phase A: fused GRU1 (64) | gh2s (192) | word(t-1)[0,200)
    {
      const long ab = ((long)(pr * 8 + wv) * 32) * 512 + lane * 8;
      const u16 *h2h = a.h2hp + ab;
      const u16 *h2l = a.h2lp + ab;
      for (int task = blk; task < 456; task += gx) {
        if (task < 64) {
          const int cg2 = task;
          f32x4 acc[3] = {{0.f, 0.f, 0.f, 0.f},
                          {0.f, 0.f, 0.f, 0.f},
                          {0.f, 0.f, 0.f, 0.f}};
          tile3<32>(acc, h2h, h2l,
                    a.W1aP + (long)cg2 * 32 * 512 + lane * 8,
                    a.W1aP + (long)(64 + cg2) * 32 * 512 + lane * 8,
                    a.W1aP + (long)(128 + cg2) * 32 * 512 + lane * 8);
          const int col = cg2 * 16 + m;
#pragma unroll
          for (int r = 0; r < 4; ++r) {
            const int row = wv * 16 + quad * 4 + r;
            const long o3 = (long)row * 3072 + col;
            const float *gc = a.gcap + ((long)t * NB + row) * 3072 + col;
            float ir = acc[0][r] + a.gv1[o3] + gc[0];
            float iz = acc[1][r] + a.gv1[o3 + 1024] + gc[1024];
            float in_ = acc[2][r] + a.gv1[o3 + 2048] + gc[2048];
            float hr = a.g1c[o3] + a.bhh1[col];
            float hz = a.g1c[o3 + 1024] + a.bhh1[1024 + col];
            float hn = a.g1c[o3 + 2048] + a.bhh1[2048 + col];
            float rr = sigmoidf_(ir + hr);
            float zz = sigmoidf_(iz + hz);
            float nn = tanhf_(in_ + rr * hn);
            const long hoff = (long)row * HID + col;
            float hnew = (1.f - zz) * nn + zz * a.h1f[(long)pr * HSZ + hoff];
            a.h1f[(long)pw * HSZ + hoff] = hnew;
            u16 hi, lo;
            split_bf16(hnew, hi, lo);
            const long po = (((long)(pw * 8 + (row >> 4)) * 32 + (col >> 5)) *
                                 64 +
                             ((col >> 3) & 3) * 16 + (row & 15)) *
                                8 +
                            (col & 7);
            a.h1hp[po] = hi;
            a.h1lp[po] = lo;
          }
        } else if (task < 256) {
          const int ct = task - 64;
          f32x4 acc = tile16p<true>(
              h2h, h2l, a.Whh2P + (long)ct * 32 * 512 + lane * 8, 32);
          const int col = ct * 16 + m;
          const float bb = a.bhh2[col];
#pragma unroll
          for (int r = 0; r < 4; ++r)
            a.gh2s[(long)(wv * 16 + quad * 4 + r) * 3072 + col] = acc[r] + bb;
        } else if (t > 0) {
          word_tile(task - 256, t - 1, pr);
        }
      }
    }
    GB();

    // Phase B: qf (64) | gi2h1 (192) | word(t-1)[200,328)
    {
      const long ab = ((long)(pw * 8 + wv) * 32) * 512 + lane * 8;
      const u16 *h1h = a.h1hp + ab;
      const u16 *h1l = a.h1lp + ab;
      for (int task = blk; task < 384; task += gx) {
        if (task < 64) {
          f32x4 acc = tile16p<true>(
              h1h, h1l, a.Wq1P + (long)task * 32 * 512 + lane * 8, 32);
          const int col = task * 16 + m;
          const float bb = a.bq1f[col];
#pragma unroll
          for (int r = 0; r < 4; ++r)
            a.qf[(long)(wv * 16 + quad * 4 + r) * HID + col] =
                fmaxf(acc[r] + bb, 0.f);
        } else if (task < 256) {
          const int ct = task - 64;
          f32x4 acc = tile16p<true>(
              h1h, h1l, a.Wih2qP + (long)ct * 32 * 512 + lane * 8, 32);
          const int col = ct * 16 + m;
#pragma unroll
          for (int r = 0; r < 4; ++r)
            a.gi2h1[(long)(wv * 16 + quad * 4 + r) * 3072 + col] = acc[r];
        } else if (t > 0) {
          word_tile(200 + (task - 256), t - 1, pr);
        }
      }
    }
    GB();

    // Phase C: attention (256) | g1c for t+1 (192) | word(t-1)[328,392)
    {
      for (int task = blk; task < 512; task += gx) {
        if (task < 256) {
          attention(t, task & 127, task >> 7);
        } else if (task < 448) {
          if (t + 1 < T_STEPS) {
            const int ct = task - 256;
            const long ab = ((long)(pw * 8 + wv) * 32) * 512 + lane * 8;
            f32x4 acc = tile16p<true>(
                a.h1hp + ab, a.h1lp + ab,
                a.Whh1P + (long)ct * 32 * 512 + lane * 8, 32);
            const int col = ct * 16 + m;
#pragma unroll
            for (int r = 0; r < 4; ++r)
              a.g1c[(long)(wv * 16 + quad * 4 + r) * 3072 + col] = acc[r];
          }
        } else if (t > 0) {
          word_tile(328 + (task - 448), t - 1, pr);
        }
      }
    }
    GB();

    // Phase D: fused GRU2 (64) | word(t-1)[392,625)
    {
      for (int task = blk; task < 297; task += gx) {
        if (task < 64) {
          const int cg2 = task;
          const long aoff = ((long)wv * 64) * 512 + lane * 8;
          f32x4 acc[3] = {{0.f, 0.f, 0.f, 0.f},
                          {0.f, 0.f, 0.f, 0.f},
                          {0.f, 0.f, 0.f, 0.f}};
          tile3<64>(acc, a.avhp + aoff, a.avlp + aoff,
                    a.Wih2aP + (long)cg2 * 64 * 512 + lane * 8,
                    a.Wih2aP + (long)(64 + cg2) * 64 * 512 + lane * 8,
                    a.Wih2aP + (long)(128 + cg2) * 64 * 512 + lane * 8);
          const int col = cg2 * 16 + m;
#pragma unroll
          for (int r = 0; r < 4; ++r) {
            const int row = wv * 16 + quad * 4 + r;
            const long o3 = (long)row * 3072 + col;
            float ir = acc[0][r] + a.gi2h1[o3] + a.bih2[col] + a.bf2f[col];
            float iz = acc[1][r] + a.gi2h1[o3 + 1024] + a.bih2[1024 + col] +
                       a.bf2f[1024 + col];
            float in_ = acc[2][r] + a.gi2h1[o3 + 2048] + a.bih2[2048 + col] +
                        a.bf2f[2048 + col];
            float hr = a.gh2s[o3];
            float hz = a.gh2s[o3 + 1024];
            float hn = a.gh2s[o3 + 2048];
            float rr = sigmoidf_(ir + hr);
            float zz = sigmoidf_(iz + hz);
            float nn = tanhf_(in_ + rr * hn);
            const long hoff = (long)row * HID + col;
            float hnew = (1.f - zz) * nn + zz * a.h2f[(long)pr * HSZ + hoff];
            a.h2f[(long)pw * HSZ + hoff] = hnew;
            u16 hi, lo;
            split_bf16(hnew, hi, lo);
            const long po = (((long)(pw * 8 + (row >> 4)) * 32 + (col >> 5)) *
                                 64 +
                             ((col >> 3) & 3) * 16 + (row & 15)) *
                                8 +
                            (col & 7);
            a.h2hp[po] = hi;
            a.h2lp[po] = lo;
          }
        } else if (t > 0) {
          word_tile(392 + (task - 64), t - 1, pr);
        }
      }
    }
    GB();
  }
  // final word(T-1): h2(18) lives in parity 1
  for (int wt = blk; wt < 625; wt += gx) word_tile(wt, T_STEPS - 1, T_STEPS & 1);
}

extern "C" void kernel_launch(void *const *d_in, const int *in_sizes, int n_in,
                              void *d_out, int out_size, void *d_ws,
                              size_t ws_size, hipStream_t stream) {
  Args a;
  a.v = (const float *)d_in[0];
  a.caption = (const float *)d_in[1];
  a.cap_len = (const int *)d_in[2];
  a.Wih1 = (const float *)d_in[3];
  a.Whh1 = (const float *)d_in[4];
  a.bih1 = (const float *)d_in[5];
  a.bhh1 = (const float *)d_in[6];
  a.Wih2 = (const float *)d_in[7];
  a.Whh2 = (const float *)d_in[8];
  a.bih2 = (const float *)d_in[9];
  a.bhh2 = (const float *)d_in[10];
  a.Wv = (const float *)d_in[11];
  a.bv = (const float *)d_in[12];
  a.Wq = (const float *)d_in[13];
  a.bq = (const float *)d_in[14];
  a.wa = (const float *)d_in[15];
  a.ba = (const float *)d_in[16];
  a.W1 = (const float *)d_in[17];
  a.b1 = (const float *)d_in[18];
  a.W2 = (const float *)d_in[19];
  a.b2 = (const float *)d_in[20];
  a.out = (float *)d_out;

  char *w = (char *)d_ws;
  size_t off = 0;
  auto take = [&](size_t bytes) -> void * {
    void *p = w + off;
    off += (bytes + 255) & ~(size_t)255;
    return p;
  };
  a.bar = (unsigned *)take(BAR_BYTES);
  a.order = (int *)take(NB * 4);
  a.dl = (int *)take(NB * 4);
  a.W1aP = (u16 *)take(3072UL * 1024 * 2);
  a.W1vP = (u16 *)take(3072UL * 2048 * 2);
  a.W1cP = (u16 *)take(3072UL * 1024 * 2);
  a.Whh1P = (u16 *)take(3072UL * 1024 * 2);
  a.Whh2P = (u16 *)take(3072UL * 1024 * 2);
  a.Wih2aP = (u16 *)take(3072UL * 2048 * 2);
  a.W2P = (u16 *)take((size_t)NTOK * 1024 * 2);
  a.Wq1P = (u16 *)take(1024UL * 1024 * 2);
  a.Wih2qP = (u16 *)take(3072UL * 1024 * 2);
  a.capphp = (u16 *)take(19UL * 8 * 32 * 512 * 2);
  a.capplp = (u16 *)take(19UL * 8 * 32 * 512 * 2);
  a.Wvh = (u16 *)take(1024UL * 2048 * 2);
  a.vh = (u16 *)take((size_t)NB * NOBJ * VDIM * 2);
  a.Wqh = (u16 *)take(1024UL * 1024 * 2);
  a.Wql = (u16 *)take(1024UL * 1024 * 2);
  a.W1T = (u16 *)take(1024UL * 1024 * 2);
  a.Wih2c = (u16 *)take(3072UL * 1024 * 2);
  a.Wih2hql = (u16 *)take(3072UL * 1024 * 2);
  a.vproj16 = (u16 *)take((size_t)NB * NOBJ * HID * 2);
  a.h1hp = (u16 *)take(2UL * 8 * 32 * 512 * 2);
  a.h1lp = (u16 *)take(2UL * 8 * 32 * 512 * 2);
  a.h2hp = (u16 *)take(2UL * 8 * 32 * 512 * 2);
  a.h2lp = (u16 *)take(2UL * 8 * 32 * 512 * 2);
  a.avhp = (u16 *)take(8UL * 64 * 512 * 2);
  a.avlp = (u16 *)take(8UL * 64 * 512 * 2);
  a.vmhp = (u16 *)take(8UL * 64 * 512 * 2);
  a.vmlp = (u16 *)take(8UL * 64 * 512 * 2);
  a.gv1 = (float *)take((size_t)NB * 3072 * 4);
  a.gh2s = (float *)take((size_t)NB * 3072 * 4);
  a.h1f = (float *)take((size_t)2 * HSZ * 4);
  a.h2f = (float *)take((size_t)2 * HSZ * 4);
  a.qf = (float *)take((size_t)HSZ * 4);
  a.gcap = (float *)take((size_t)T_STEPS * NB * 3072 * 4);
  a.g1c = (float *)take((size_t)NB * 3072 * 4);
  a.gi2h1 = (float *)take((size_t)NB * 3072 * 4);
  a.bq1f = (float *)take(1024UL * 4);
  a.bf2f = (float *)take(3072UL * 4);

  static int gridBlocks = 0;
  if (gridBlocks == 0) {
    int occ = 0;
    if (hipOccupancyMaxActiveBlocksPerMultiprocessor(&occ, (const void *)butd,
                                                     512, 0) != hipSuccess ||
        occ < 1)
      occ = 1;
    gridBlocks = (occ >= 2) ? 512 : 256;
  }

  (void)hipMemsetAsync((void *)a.bar, 0, BAR_BYTES, stream);
  void *kargs[] = {(void *)&a};
  hipLaunchCooperativeKernel((const void *)butd, dim3(gridBlocks), dim3(512),
                             kargs, 0, stream);
}

// Round 7
// 7435.091 us; speedup vs baseline: 1.2508x; 1.2508x over previous
//
#include <hip/hip_runtime.h>

typedef unsigned short u16;
typedef __attribute__((ext_vector_type(8))) short bf16x8;
typedef __attribute__((ext_vector_type(4))) float f32x4;

#define NB 128
#define NOBJ 36
#define VDIM 2048
#define EMB 1024
#define HID 1024
#define NTOK 10000
#define MAXLEN 20
#define T_STEPS 19
#define PRED_STRIDE (MAXLEN * NTOK)          /* 200000 */
#define ALPHA_OFF ((long)NB * MAXLEN * NTOK) /* 25,600,000 */
#define HSZ (NB * HID)                       /* 131072 */
#define BAR_GEN (512 * 16)
#define WD_OFF (512 * 16 + 16)
#define BAR_BYTES ((512 * 16 + 16 + 64) * 4)

struct Args {
  const float *v, *caption;
  const int *cap_len;
  const float *Wih1, *Whh1, *bih1, *bhh1, *Wih2, *Whh2, *bih2, *bhh2;
  const float *Wv, *bv, *Wq, *bq, *wa, *ba, *W1, *b1, *W2, *b2;
  float *out;
  unsigned *bar;
  int *order, *dl;
  u16 *Wvh, *vh, *Wqh, *Wql, *W1T, *Wih2c, *Wih2hql, *vproj16;
  // fragment-packed GEMM operands: [colgrp][K/32][64 lanes][8]
  u16 *W1aP, *W1vP, *W1cP, *Whh1P, *Whh2P, *Wih2aP, *W2P, *Wq1P, *Wih2qP;
  u16 *capphp, *capplp;
  u16 *h1hp, *h1lp, *h2hp, *h2lp, *avhp, *avlp, *vmhp, *vmlp;
  float *gv1, *gh2s, *h1f, *h2f, *gcap, *g1c, *gi2h1, *qf;
  float *bq1f, *bf2f;
};

__device__ inline float b2f(u16 h) {
  unsigned u = ((unsigned)h) << 16;
  float f;
  __builtin_memcpy(&f, &u, 4);
  return f;
}
__device__ inline u16 f2b_trunc(float x) {
  unsigned u;
  __builtin_memcpy(&u, &x, 4);
  return (u16)(u >> 16);
}
__device__ inline u16 f2b_rne(float x) {
  unsigned u;
  __builtin_memcpy(&u, &x, 4);
  unsigned r = (u + 0x7fffu + ((u >> 16) & 1u)) >> 16;
  return (u16)r;
}
__device__ inline void split_bf16(float x, u16 &hi, u16 &lo) {
  hi = f2b_trunc(x);
  lo = f2b_trunc(x - b2f(hi));
}
__device__ inline bf16x8 ldb8(const u16 *p) {
  uint4 u = *(const uint4 *)p;
  bf16x8 v;
  __builtin_memcpy(&v, &u, 16);
  return v;
}
__device__ inline f32x4 mfma16(bf16x8 a, bf16x8 b, f32x4 c) {
  return __builtin_amdgcn_mfma_f32_16x16x32_bf16(a, b, c, 0, 0, 0);
}
__device__ inline float sigmoidf_(float x) {
  float e = __expf(-fabsf(x));
  float p = 1.f / (1.f + e);
  return x >= 0.f ? p : 1.f - p;
}
__device__ inline float tanhf_(float x) {
  float e = __expf(-2.f * fabsf(x));
  float t = (1.f - e) / (1.f + e);
  return x >= 0.f ? t : -t;
}
__device__ inline float wred_sum(float x) {
#pragma unroll
  for (int off = 32; off > 0; off >>= 1) x += __shfl_xor(x, off, 64);
  return x;
}
__device__ inline float wred_max(float x) {
#pragma unroll
  for (int off = 32; off > 0; off >>= 1) x = fmaxf(x, __shfl_xor(x, off, 64));
  return x;
}
__device__ inline void ntstf(float *p, float v) {
  __builtin_nontemporal_store(v, p);
}
__device__ inline f32x4 ntld4(const float *p) {
  return __builtin_nontemporal_load((const f32x4 *)p);
}
__device__ inline unsigned ald(const unsigned *p) {
  return __hip_atomic_load(p, __ATOMIC_RELAXED, __HIP_MEMORY_SCOPE_AGENT);
}

// store-arrival barrier among blocks [0, nblk); block 0 is the scanner.
__device__ inline void gbar(unsigned *bar, int blk, int nblk, unsigned target) {
  __syncthreads();
  __threadfence();
  if (threadIdx.x == 0)
    __hip_atomic_store(&bar[blk * 16], target, __ATOMIC_RELAXED,
                       __HIP_MEMORY_SCOPE_AGENT);
  if (blk == 0) {
    for (int s = threadIdx.x; s < nblk; s += 512) {
      while (ald(&bar[s * 16]) < target) __builtin_amdgcn_s_sleep(2);
    }
    __syncthreads();
    if (threadIdx.x == 0) {
      __threadfence();
      __hip_atomic_store(&bar[BAR_GEN], target, __ATOMIC_RELAXED,
                         __HIP_MEMORY_SCOPE_AGENT);
    }
  } else if (threadIdx.x == 0) {
    while (ald(&bar[BAR_GEN]) < target) __builtin_amdgcn_s_sleep(2);
  }
  __syncthreads();
  __threadfence();
}

// f32 -> bf16(RNE), grid-strided, NT loads (one-shot data)
__device__ inline void cvt_hi(const float *src, u16 *dst, long n, long g0,
                              long gs) {
  for (long i = g0 * 4; i < n; i += gs * 4) {
    f32x4 f = ntld4(src + i);
    ushort4 o;
    o.x = f2b_rne(f[0]);
    o.y = f2b_rne(f[1]);
    o.z = f2b_rne(f[2]);
    o.w = f2b_rne(f[3]);
    *(ushort4 *)(dst + i) = o;
  }
}
__device__ inline void cvt_split(const float *src, u16 *dhi, u16 *dlo, long n,
                                 long g0, long gs) {
  for (long i = g0 * 4; i < n; i += gs * 4) {
    f32x4 f = ntld4(src + i);
    ushort4 h, l;
    split_bf16(f[0], h.x, l.x);
    split_bf16(f[1], h.y, l.y);
    split_bf16(f[2], h.z, l.z);
    split_bf16(f[3], h.w, l.w);
    *(ushort4 *)(dhi + i) = h;
    *(ushort4 *)(dlo + i) = l;
  }
}

// pack W[O][Ksrc] (f32, RNE) window [k0, k0+K) into fragment-major layout
__device__ inline void packW(const float *src, u16 *dst, int O, int K, int Ksrc,
                             int k0, long g0, long gs) {
  const int kblk = K >> 5;
  const long nfrag = (long)(O >> 4) * kblk * 64;
  for (long f = g0; f < nfrag; f += gs) {
    const int lane_ = (int)(f & 63);
    const long cgks = f >> 6;
    const int ks = (int)(cgks % kblk);
    const int colg = (int)(cgks / kblk);
    const int col = colg * 16 + (lane_ & 15);
    const int k = k0 + ks * 32 + (lane_ >> 4) * 8;
    const float *s = src + (long)col * Ksrc + k;
    f32x4 f0 = ntld4(s), f1 = ntld4(s + 4);
    ushort4 o0, o1;
    o0.x = f2b_rne(f0[0]);
    o0.y = f2b_rne(f0[1]);
    o0.z = f2b_rne(f0[2]);
    o0.w = f2b_rne(f0[3]);
    o1.x = f2b_rne(f1[0]);
    o1.y = f2b_rne(f1[1]);
    o1.z = f2b_rne(f1[2]);
    o1.w = f2b_rne(f1[3]);
    *(ushort4 *)(dst + f * 8) = o0;
    *(ushort4 *)(dst + f * 8 + 4) = o1;
  }
}

// ---------------- linear-layout GEMM helpers (one-shot phases only) --------
#define MMK_BODY                                                               \
  {                                                                            \
    const int ko = ks * 32;                                                    \
    bf16x8 va = ldb8(ah + ko);                                                 \
    bf16x8 vl;                                                                 \
    if constexpr (SPLIT) vl = ldb8(al + ko);                                   \
    _Pragma("unroll") for (int i = 0; i < NT; ++i) {                           \
      bf16x8 vb = ldb8(wr + (long)i * wstride + ko);                           \
      acc[i] = mfma16(va, vb, acc[i]);                                         \
      if constexpr (SPLIT) acc[i] = mfma16(vl, vb, acc[i]);                    \
    }                                                                          \
  }

template <int NT, bool SPLIT>
__device__ inline void mmk(f32x4 *acc, const u16 *ah, const u16 *al,
                           const u16 *wr, long wstride, int ksteps) {
#pragma unroll 2
  for (int ks = 0; ks < ksteps; ++ks) MMK_BODY
}

template <bool SPLIT>
__device__ inline f32x4 tile16(const u16 *ah, const u16 *al, const u16 *wr,
                               int K) {
  f32x4 acch = {0.f, 0.f, 0.f, 0.f};
  f32x4 accl = {0.f, 0.f, 0.f, 0.f};
  const int ksteps = K >> 5;
#pragma unroll 4
  for (int ks = 0; ks < ksteps; ++ks) {
    const int ko = ks * 32;
    bf16x8 vb = ldb8(wr + ko);
    acch = mfma16(ldb8(ah + ko), vb, acch);
    if constexpr (SPLIT) accl = mfma16(ldb8(al + ko), vb, accl);
  }
  if constexpr (SPLIT) {
#pragma unroll
    for (int r = 0; r < 4; ++r) acch[r] += accl[r];
  }
  return acch;
}

// packed GEMM: pointers pre-offset to (tile, lane); every load = 1KB/wave.
template <bool SPLIT>
__device__ inline f32x4 tile16p(const u16 *ah, const u16 *al, const u16 *bp,
                                int ksteps) {
  f32x4 acch = {0.f, 0.f, 0.f, 0.f};
  f32x4 accl = {0.f, 0.f, 0.f, 0.f};
#pragma unroll 4
  for (int ks = 0; ks < ksteps; ++ks) {
    bf16x8 vb = ldb8(bp + ks * 512);
    acch = mfma16(ldb8(ah + ks * 512), vb, acch);
    if constexpr (SPLIT) accl = mfma16(ldb8(al + ks * 512), vb, accl);
  }
  if constexpr (SPLIT) {
#pragma unroll
    for (int r = 0; r < 4; ++r) acch[r] += accl[r];
  }
  return acch;
}

// 3-gate packed GEMM: shared split-A, 3 B tiles (for fused GRU phases)
template <int KSTEPS>
__device__ inline void tile3(f32x4 acc[3], const u16 *ah, const u16 *al,
                             const u16 *b0, const u16 *b1, const u16 *b2) {
#pragma unroll 2
  for (int ks = 0; ks < KSTEPS; ++ks) {
    bf16x8 va = ldb8(ah + ks * 512);
    bf16x8 vl = ldb8(al + ks * 512);
    bf16x8 w0 = ldb8(b0 + ks * 512);
    bf16x8 w1 = ldb8(b1 + ks * 512);
    bf16x8 w2 = ldb8(b2 + ks * 512);
    acc[0] = mfma16(va, w0, acc[0]);
    acc[1] = mfma16(va, w1, acc[1]);
    acc[2] = mfma16(va, w2, acc[2]);
    acc[0] = mfma16(vl, w0, acc[0]);
    acc[1] = mfma16(vl, w1, acc[1]);
    acc[2] = mfma16(vl, w2, acc[2]);
  }
}

__global__ void __launch_bounds__(512, 4) butd(Args a) {
  const int tid = threadIdx.x;
  const int blk = blockIdx.x;
  const int gx = gridDim.x;
  const int lane = tid & 63;
  const int wv = tid >> 6;
  const int m = lane & 15;
  const int quad = lane >> 4;
  __shared__ float sl[64];

  const long gs = (long)gx * 512;
  const long g0 = (long)blk * 512 + tid;
  const int SP = gx >> 1;       // serial pool size
  const int NW = gx - SP;       // word pool size

  //================= P0: pack/convert weights + argsort + zero-init =========
  packW(a.Wih1, a.W1aP, 3072, 1024, 4096, 0, g0, gs);
  packW(a.Wih1, a.W1vP, 3072, 2048, 4096, 1024, g0, gs);
  packW(a.Wih1, a.W1cP, 3072, 1024, 4096, 3072, g0, gs);
  packW(a.Whh1, a.Whh1P, 3072, 1024, 1024, 0, g0, gs);
  packW(a.Whh2, a.Whh2P, 3072, 1024, 1024, 0, g0, gs);
  packW(a.Wih2, a.Wih2aP, 3072, 2048, 3072, 0, g0, gs);
  packW(a.W2, a.W2P, NTOK, 1024, 1024, 0, g0, gs);
  cvt_hi(a.Wv, a.Wvh, 1024L * 2048, g0, gs);
  cvt_hi(a.v, a.vh, (long)NB * NOBJ * VDIM, g0, gs);
  cvt_split(a.Wq, a.Wqh, a.Wql, 1024L * 1024, g0, gs);
  for (long i = g0; i < 1024L * 1024; i += gs) {
    const int ii = (int)(i >> 10), mm2 = (int)(i & 1023);
    a.W1T[i] = f2b_rne(a.W1[(long)mm2 * 1024 + ii]);
  }
  for (long i = g0 * 4; i < 3072L * 1024; i += gs * 4) {
    const int row = (int)(i >> 10), c = (int)(i & 1023);
    f32x4 f = ntld4(a.Wih2 + (long)row * 3072 + 2048 + c);
    ushort4 h, l;
    h.x = f2b_rne(f[0]);
    h.y = f2b_rne(f[1]);
    h.z = f2b_rne(f[2]);
    h.w = f2b_rne(f[3]);
    l.x = f2b_trunc(f[0] - b2f(h.x));
    l.y = f2b_trunc(f[1] - b2f(h.y));
    l.z = f2b_trunc(f[2] - b2f(h.z));
    l.w = f2b_trunc(f[3] - b2f(h.w));
    *(ushort4 *)(a.Wih2c + i) = h;
    *(ushort4 *)(a.Wih2hql + i) = l;
  }

  if (blk == 0 && tid < NB) {
    int ki = a.cap_len[tid];
    int rank = 0;
    for (int j = 0; j < NB; ++j) {
      int kj = a.cap_len[j];
      rank += (kj > ki) || (kj == ki && j < tid);
    }
    a.order[rank] = tid;
    a.dl[rank] = ki - 1;
  }
  for (long i = g0; i < (long)NB * NTOK; i += gs) {
    long b = i / NTOK, n = i - b * NTOK;
    ntstf(&a.out[b * PRED_STRIDE + (long)(MAXLEN - 1) * NTOK + n], 0.f);
  }
  for (long i = g0; i < (long)NB * NOBJ; i += gs) {
    long b = i / NOBJ, n = i - b * NOBJ;
    ntstf(&a.out[ALPHA_OFF + b * (MAXLEN * NOBJ) + (MAXLEN - 1) * NOBJ + n],
          0.f);
  }
  for (long i = g0; i < HSZ; i += gs) {
    a.h1f[i] = 0.f;
    a.h2f[i] = 0.f;
    a.h1hp[i] = 0;
    a.h1lp[i] = 0;
    a.h2hp[i] = 0;
    a.h2lp[i] = 0;
  }
  for (long i = g0; i < 128L * 3072; i += gs) a.g1c[i] = 0.f;
  gbar(a.bar, blk, gx, 1);

  //================= P1: v_mean(packed) + caption pack + vproj + bias folds =
  for (int b = blk; b < NB; b += gx) {
    const int ob = a.order[b];
    if (tid < 256) {
      const int d0 = tid * 8;
      const float *vb = a.v + (long)ob * NOBJ * VDIM + d0;
      float s[8] = {};
      for (int k = 0; k < NOBJ; ++k) {
        f32x4 x0 = *(const f32x4 *)(vb + (long)k * VDIM);
        f32x4 x1 = *(const f32x4 *)(vb + (long)k * VDIM + 4);
#pragma unroll
        for (int j = 0; j < 4; ++j) {
          s[j] += x0[j];
          s[4 + j] += x1[j];
        }
      }
#pragma unroll
      for (int j = 0; j < 8; ++j) s[j] *= (1.f / 36.f);
      ushort4 H0, H1, L0, L1;
      split_bf16(s[0], H0.x, L0.x);
      split_bf16(s[1], H0.y, L0.y);
      split_bf16(s[2], H0.z, L0.z);
      split_bf16(s[3], H0.w, L0.w);
      split_bf16(s[4], H1.x, L1.x);
      split_bf16(s[5], H1.y, L1.y);
      split_bf16(s[6], H1.z, L1.z);
      split_bf16(s[7], H1.w, L1.w);
      const long po = (((long)(b >> 4) * 64 + (d0 >> 5)) * 64 +
                       ((d0 >> 3) & 3) * 16 + (b & 15)) *
                      8;
      *(ushort4 *)(a.vmhp + po) = H0;
      *(ushort4 *)(a.vmhp + po + 4) = H1;
      *(ushort4 *)(a.vmlp + po) = L0;
      *(ushort4 *)(a.vmlp + po + 4) = L1;
    }
  }
  for (long f = g0; f < 19L * 8 * 32 * 64; f += gs) {
    const int lane_ = (int)(f & 63);
    long rest = f >> 6;
    const int ks = (int)(rest & 31);
    rest >>= 5;
    const int tile = (int)(rest & 7);
    const int t = (int)(rest >> 3);
    const int b = a.order[tile * 16 + (lane_ & 15)];
    const int k = ks * 32 + (lane_ >> 4) * 8;
    const float *s = a.caption + ((long)b * MAXLEN + t) * EMB + k;
    f32x4 f0 = ntld4(s), f1 = ntld4(s + 4);
    ushort4 H0, H1, L0, L1;
    split_bf16(f0[0], H0.x, L0.x);
    split_bf16(f0[1], H0.y, L0.y);
    split_bf16(f0[2], H0.z, L0.z);
    split_bf16(f0[3], H0.w, L0.w);
    split_bf16(f1[0], H1.x, L1.x);
    split_bf16(f1[1], H1.y, L1.y);
    split_bf16(f1[2], H1.z, L1.z);
    split_bf16(f1[3], H1.w, L1.w);
    *(ushort4 *)(a.capphp + f * 8) = H0;
    *(ushort4 *)(a.capphp + f * 8 + 4) = H1;
    *(ushort4 *)(a.capplp + f * 8) = L0;
    *(ushort4 *)(a.capplp + f * 8 + 4) = L1;
  }
  for (int tt = blk; tt < 576; tt += gx) {
    const int mg = tt % 36, ngr = tt / 36;
    const int row = mg * 128 + wv * 16 + m;
    const int bb = row / NOBJ, ko = row - bb * NOBJ;
    const u16 *ar = a.vh + ((long)a.order[bb] * NOBJ + ko) * VDIM + quad * 8;
    const int c0 = ngr * 64;
    const u16 *wr = a.Wvh + (long)(c0 + m) * VDIM + quad * 8;
    f32x4 acc[4] = {};
    mmk<4, false>(acc, ar, nullptr, wr, 16L * VDIM, VDIM / 32);
#pragma unroll
    for (int i = 0; i < 4; ++i) {
      const int col = c0 + i * 16 + m;
      const float bvv = a.bv[col];
#pragma unroll
      for (int r = 0; r < 4; ++r) {
        const int grow = mg * 128 + wv * 16 + quad * 4 + r;
        a.vproj16[(long)grow * HID + col] = f2b_rne(fmaxf(acc[i][r] + bvv, 0.f));
      }
    }
  }
  for (int o = blk * 8 + wv; o < 4096; o += gx * 8) {
    if (o < 1024) {
      float s = 0.f;
      for (int c = lane; c < 1024; c += 64) s += a.Wq[(long)o * 1024 + c] * a.b1[c];
      s = wred_sum(s);
      if (lane == 0) a.bq1f[o] = s + a.bq[o];
    } else {
      const int oo = o - 1024;
      float s = 0.f;
      for (int c = lane; c < 1024; c += 64)
        s += a.Wih2[(long)oo * 3072 + 2048 + c] * a.b1[c];
      s = wred_sum(s);
      if (lane == 0) a.bf2f[oo] = s;
    }
  }
  gbar(a.bar, blk, gx, 2);

  //== P2: gv1, gcap (all t), fold GEMMs (outputs packed) ====================
  for (int task = blk; task < 5888; task += gx) {
    if (task < 192) {
      const u16 *ah = a.vmhp + (long)wv * 64 * 512 + lane * 8;
      const u16 *al = a.vmlp + (long)wv * 64 * 512 + lane * 8;
      f32x4 acc = tile16p<true>(ah, al,
                                a.W1vP + (long)task * 64 * 512 + lane * 8, 64);
      const int col = task * 16 + m;
      const float bb = a.bih1[col];
#pragma unroll
      for (int r = 0; r < 4; ++r)
        a.gv1[(long)(wv * 16 + quad * 4 + r) * 3072 + col] = acc[r] + bb;
    } else if (task < 3840) {
      const int tt2 = task - 192;
      const int tdx = tt2 / 192, ct = tt2 % 192;
      const u16 *ah = a.capphp + ((long)(tdx * 8 + wv) * 32) * 512 + lane * 8;
      const u16 *al = a.capplp + ((long)(tdx * 8 + wv) * 32) * 512 + lane * 8;
      f32x4 acc =
          tile16p<true>(ah, al, a.W1cP + (long)ct * 32 * 512 + lane * 8, 32);
      const int col = ct * 16 + m;
#pragma unroll
      for (int r = 0; r < 4; ++r)
        a.gcap[((long)tdx * NB + wv * 16 + quad * 4 + r) * 3072 + col] = acc[r];
    } else if (task < 4352) {
      const int tt2 = task - 3840;
      const int rg = tt2 >> 6, ct = tt2 & 63;
      const int row = rg * 128 + wv * 16 + m, col = ct * 16 + m;
      f32x4 acc = tile16<true>(a.Wqh + (long)row * HID + quad * 8,
                               a.Wql + (long)row * HID + quad * 8,
                               a.W1T + (long)col * HID + quad * 8, HID);
#pragma unroll
      for (int r = 0; r < 4; ++r) {
        const int n = rg * 128 + wv * 16 + quad * 4 + r;
        a.Wq1P[((long)(n >> 4) * 32 + (col >> 5)) * 512 +
               (((col >> 3) & 3) * 16 + (n & 15)) * 8 + (col & 7)] =
            f2b_rne(acc[r]);
      }
    } else {
      const int tt2 = task - 4352;
      const int rg = tt2 >> 6, ct = tt2 & 63;
      const int row = rg * 128 + wv * 16 + m, col = ct * 16 + m;
      f32x4 acc = tile16<true>(a.Wih2c + (long)row * 1024 + quad * 8,
                               a.Wih2hql + (long)row * 1024 + quad * 8,
                               a.W1T + (long)col * HID + quad * 8, HID);
#pragma unroll
      for (int r = 0; r < 4; ++r) {
        const int n = rg * 128 + wv * 16 + quad * 4 + r;
        a.Wih2qP[((long)(n >> 4) * 32 + (col >> 5)) * 512 +
                 (((col >> 3) & 3) * 16 + (n & 15)) * 8 + (col & 7)] =
            f2b_rne(acc[r]);
      }
    }
  }
  gbar(a.bar, blk, gx, 3);

  //================= shared lambdas =========================================
  auto word_tile = [&](int wt, int tf, int pb) {
    const long ab = ((long)(pb * 8 + wv) * 32) * 512 + lane * 8;
    f32x4 acc = tile16p<true>(a.h2hp + ab, a.h2lp + ab,
                              a.W2P + (long)wt * 32 * 512 + lane * 8, 32);
    const int col = wt * 16 + m;
    const float bb = a.b2[col];
#pragma unroll
    for (int r = 0; r < 4; ++r) {
      const int grow = wv * 16 + quad * 4 + r;
      const int msk = tf < a.dl[grow];
      ntstf(&a.out[(long)grow * PRED_STRIDE + (long)tf * NTOK + col],
            msk ? acc[r] + bb : 0.f);
    }
  };

  auto attention = [&](int t, int b, int half) {
    __syncthreads();
    const int ob = a.order[b];
    const float *qrow = a.qf + (long)b * HID;
    for (int k = wv; k < NOBJ; k += 8) {
      const u16 *vp = a.vproj16 + ((long)b * NOBJ + k) * HID;
      float s = 0.f;
#pragma unroll
      for (int dd = 0; dd < 2; ++dd) {
        const int d = dd * 512 + lane * 8;
        bf16x8 vv = ldb8(vp + d);
        f32x4 q0 = *(const f32x4 *)(qrow + d);
        f32x4 q1 = *(const f32x4 *)(qrow + d + 4);
        f32x4 w0 = *(const f32x4 *)(a.wa + d);
        f32x4 w1 = *(const f32x4 *)(a.wa + d + 4);
#pragma unroll
        for (int j = 0; j < 4; ++j) {
          s += b2f((u16)vv[j]) * q0[j] * w0[j];
          s += b2f((u16)vv[4 + j]) * q1[j] * w1[j];
        }
      }
      s = wred_sum(s);
      if (lane == 0) sl[k] = s + a.ba[0];
    }
    __syncthreads();
    if (wv == 0) {
      float x = (lane < NOBJ) ? sl[lane] : -3.0e38f;
      float mx = wred_max(x);
      float e = (lane < NOBJ) ? __expf(x - mx) : 0.f;
      float den = wred_sum(e);
      float att = e / den;
      if (lane < NOBJ) {
        sl[lane] = att;
        if (half == 0) {
          const int msk = t < a.dl[b];
          ntstf(&a.out[ALPHA_OFF + (long)b * (MAXLEN * NOBJ) + t * NOBJ + lane],
                msk ? att : 0.f);
        }
      }
    }
    __syncthreads();
    if (tid < 128) {
      const int d0 = half * 1024 + tid * 8;
      const u16 *vb = a.vh + (long)ob * NOBJ * VDIM + d0;
      float s[8] = {};
      for (int k = 0; k < NOBJ; ++k) {
        bf16x8 vv = ldb8(vb + (long)k * VDIM);
        const float w = sl[k];
#pragma unroll
        for (int j = 0; j < 8; ++j) s[j] += w * b2f((u16)vv[j]);
      }
      ushort4 H0, H1, L0, L1;
      split_bf16(s[0], H0.x, L0.x);
      split_bf16(s[1], H0.y, L0.y);
      split_bf16(s[2], H0.z, L0.z);
      split_bf16(s[3], H0.w, L0.w);
      split_bf16(s[4], H1.x, L1.x);
      split_bf16(s[5], H1.y, L1.y);
      split_bf16(s[6], H1.z, L1.z);
      split_bf16(s[7], H1.w, L1.w);
      const long po = (((long)(b >> 4) * 64 + (d0 >> 5)) * 64 +
                       ((d0 >> 3) & 3) * 16 + (b & 15)) *
                      8;
      *(ushort4 *)(a.avhp + po) = H0;
      *(ushort4 *)(a.avhp + po + 4) = H1;
      *(ushort4 *)(a.avlp + po) = L0;
      *(ushort4 *)(a.avlp + po + 4) = L1;
    }
  };

  //================= time loop: S-pool chain, W-pool background words =======
  if (blk < SP) {
    unsigned bgen = 4;
    for (int t = 0; t < T_STEPS; ++t) {
      const int pr = t & 1, pw = pr ^ 1;

      // Phase A: fused GRU1 (0..63) | gh2s (64..255)
      {
        const long ab = ((long)(pr * 8 + wv) * 32) * 512 + lane * 8;
        const u16 *h2h = a.h2hp + ab;
        const u16 *h2l = a.h2lp + ab;
        for (int task = blk; task < 256; task += SP) {
          if (task < 64) {
            const int cg2 = task;
            f32x4 acc[3] = {{0.f, 0.f, 0.f, 0.f},
                            {0.f, 0.f, 0.f, 0.f},
                            {0.f, 0.f, 0.f, 0.f}};
            tile3<32>(acc, h2h, h2l,
                      a.W1aP + (long)cg2 * 32 * 512 + lane * 8,
                      a.W1aP + (long)(64 + cg2) * 32 * 512 + lane * 8,
                      a.W1aP + (long)(128 + cg2) * 32 * 512 + lane * 8);
            const int col = cg2 * 16 + m;
#pragma unroll
            for (int r = 0; r < 4; ++r) {
              const int row = wv * 16 + quad * 4 + r;
              const long o3 = (long)row * 3072 + col;
              const float *gc = a.gcap + ((long)t * NB + row) * 3072 + col;
              float ir = acc[0][r] + a.gv1[o3] + gc[0];
              float iz = acc[1][r] + a.gv1[o3 + 1024] + gc[1024];
              float in_ = acc[2][r] + a.gv1[o3 + 2048] + gc[2048];
              float hr = a.g1c[o3] + a.bhh1[col];
              float hz = a.g1c[o3 + 1024] + a.bhh1[1024 + col];
              float hn = a.g1c[o3 + 2048] + a.bhh1[2048 + col];
              float rr = sigmoidf_(ir + hr);
              float zz = sigmoidf_(iz + hz);
              float nn = tanhf_(in_ + rr * hn);
              const long hoff = (long)row * HID + col;
              float hnew = (1.f - zz) * nn + zz * a.h1f[(long)pr * HSZ + hoff];
              a.h1f[(long)pw * HSZ + hoff] = hnew;
              u16 hi, lo;
              split_bf16(hnew, hi, lo);
              const long po =
                  (((long)(pw * 8 + (row >> 4)) * 32 + (col >> 5)) * 64 +
                   ((col >> 3) & 3) * 16 + (row & 15)) *
                      8 +
                  (col & 7);
              a.h1hp[po] = hi;
              a.h1lp[po] = lo;
            }
          } else {
            const int ct = task - 64;
            f32x4 acc = tile16p<true>(
                h2h, h2l, a.Whh2P + (long)ct * 32 * 512 + lane * 8, 32);
            const int col = ct * 16 + m;
            const float bb = a.bhh2[col];
#pragma unroll
            for (int r = 0; r < 4; ++r)
              a.gh2s[(long)(wv * 16 + quad * 4 + r) * 3072 + col] = acc[r] + bb;
          }
        }
      }
      gbar(a.bar, blk, SP, bgen++);

      // Phase B: qf (0..63) | gi2h1 (64..255)
      {
        const long ab = ((long)(pw * 8 + wv) * 32) * 512 + lane * 8;
        const u16 *h1h = a.h1hp + ab;
        const u16 *h1l = a.h1lp + ab;
        for (int task = blk; task < 256; task += SP) {
          if (task < 64) {
            f32x4 acc = tile16p<true>(
                h1h, h1l, a.Wq1P + (long)task * 32 * 512 + lane * 8, 32);
            const int col = task * 16 + m;
            const float bb = a.bq1f[col];
#pragma unroll
            for (int r = 0; r < 4; ++r)
              a.qf[(long)(wv * 16 + quad * 4 + r) * HID + col] =
                  fmaxf(acc[r] + bb, 0.f);
          } else {
            const int ct = task - 64;
            f32x4 acc = tile16p<true>(
                h1h, h1l, a.Wih2qP + (long)ct * 32 * 512 + lane * 8, 32);
            const int col = ct * 16 + m;
#pragma unroll
            for (int r = 0; r < 4; ++r)
              a.gi2h1[(long)(wv * 16 + quad * 4 + r) * 3072 + col] = acc[r];
          }
        }
      }
      gbar(a.bar, blk, SP, bgen++);

      // Phase C: attention (0..255)
      for (int task = blk; task < 256; task += SP)
        attention(t, task & 127, task >> 7);
      gbar(a.bar, blk, SP, bgen++);

      // Phase D: wait W-pool done with words reading parity pw, then
      //          fused GRU2 (0..63) | g1c for t+1 (64..255)
      if (t >= 2) {
        if (tid == 0) {
          while (ald(&a.bar[WD_OFF + (t - 2)]) < (unsigned)NW)
            __builtin_amdgcn_s_sleep(4);
        }
        __syncthreads();
      }
      for (int task = blk; task < 256; task += SP) {
        if (task < 64) {
          const int cg2 = task;
          const long aoff = ((long)wv * 64) * 512 + lane * 8;
          f32x4 acc[3] = {{0.f, 0.f, 0.f, 0.f},
                          {0.f, 0.f, 0.f, 0.f},
                          {0.f, 0.f, 0.f, 0.f}};
          tile3<64>(acc, a.avhp + aoff, a.avlp + aoff,
                    a.Wih2aP + (long)cg2 * 64 * 512 + lane * 8,
                    a.Wih2aP + (long)(64 + cg2) * 64 * 512 + lane * 8,
                    a.Wih2aP + (long)(128 + cg2) * 64 * 512 + lane * 8);
          const int col = cg2 * 16 + m;
#pragma unroll
          for (int r = 0; r < 4; ++r) {
            const int row = wv * 16 + quad * 4 + r;
            const long o3 = (long)row * 3072 + col;
            float ir = acc[0][r] + a.gi2h1[o3] + a.bih2[col] + a.bf2f[col];
            float iz = acc[1][r] + a.gi2h1[o3 + 1024] + a.bih2[1024 + col] +
                       a.bf2f[1024 + col];
            float in_ = acc[2][r] + a.gi2h1[o3 + 2048] + a.bih2[2048 + col] +
                        a.bf2f[2048 + col];
            float hr = a.gh2s[o3];
            float hz = a.gh2s[o3 + 1024];
            float hn = a.gh2s[o3 + 2048];
            float rr = sigmoidf_(ir + hr);
            float zz = sigmoidf_(iz + hz);
            float nn = tanhf_(in_ + rr * hn);
            const long hoff = (long)row * HID + col;
            float hnew = (1.f - zz) * nn + zz * a.h2f[(long)pr * HSZ + hoff];
            a.h2f[(long)pw * HSZ + hoff] = hnew;
            u16 hi, lo;
            split_bf16(hnew, hi, lo);
            const long po =
                (((long)(pw * 8 + (row >> 4)) * 32 + (col >> 5)) * 64 +
                 ((col >> 3) & 3) * 16 + (row & 15)) *
                    8 +
                (col & 7);
            a.h2hp[po] = hi;
            a.h2lp[po] = lo;
          }
        } else if (t + 1 < T_STEPS) {
          const int ct = task - 64;
          const long ab = ((long)(pw * 8 + wv) * 32) * 512 + lane * 8;
          f32x4 acc = tile16p<true>(a.h1hp + ab, a.h1lp + ab,
                                    a.Whh1P + (long)ct * 32 * 512 + lane * 8,
                                    32);
          const int col = ct * 16 + m;
#pragma unroll
          for (int r = 0; r < 4; ++r)
            a.g1c[(long)(wv * 16 + quad * 4 + r) * 3072 + col] = acc[r];
        }
      }
      gbar(a.bar, blk, SP, bgen++);
    }
  } else {
    //================= W-pool: background word GEMMs ========================
    const int wi = blk - SP;
    for (int t = 0; t < T_STEPS; ++t) {
      const unsigned need = 3 + 4 * t + 4; // gen after S phase D of step t
      if (tid == 0) {
        while (ald(&a.bar[BAR_GEN]) < need) __builtin_amdgcn_s_sleep(4);
      }
      __syncthreads();
      __threadfence();
      const int pb = (t + 1) & 1;
      for (int wt = wi; wt < 625; wt += NW) word_tile(wt, t, pb);
      __threadfence(); // drain reads+writes before signaling
      if (tid == 0)
        __hip_atomic_fetch_add(&a.bar[WD_OFF + t], 1u, __ATOMIC_RELEASE,
                               __HIP_MEMORY_SCOPE_AGENT);
    }
  }
}

extern "C" void kernel_launch(void *const *d_in, const int *in_sizes, int n_in,
                              void *d_out, int out_size, void *d_ws,
                              size_t ws_size, hipStream_t stream) {
  Args a;
  a.v = (const float *)d_in[0];
  a.caption = (const float *)d_in[1];
  a.cap_len = (const int *)d_in[2];
  a.Wih1 = (const float *)d_in[3];
  a.Whh1 = (const float *)d_in[4];
  a.bih1 = (const float *)d_in[5];
  a.bhh1 = (const float *)d_in[6];
  a.Wih2 = (const float *)d_in[7];
  a.Whh2 = (const float *)d_in[8];
  a.bih2 = (const float *)d_in[9];
  a.bhh2 = (const float *)d_in[10];
  a.Wv = (const float *)d_in[11];
  a.bv = (const float *)d_in[12];
  a.Wq = (const float *)d_in[13];
  a.bq = (const float *)d_in[14];
  a.wa = (const float *)d_in[15];
  a.ba = (const float *)d_in[16];
  a.W1 = (const float *)d_in[17];
  a.b1 = (const float *)d_in[18];
  a.W2 = (const float *)d_in[19];
  a.b2 = (const float *)d_in[20];
  a.out = (float *)d_out;

  char *w = (char *)d_ws;
  size_t off = 0;
  auto take = [&](size_t bytes) -> void * {
    void *p = w + off;
    off += (bytes + 255) & ~(size_t)255;
    return p;
  };
  a.bar = (unsigned *)take(BAR_BYTES);
  a.order = (int *)take(NB * 4);
  a.dl = (int *)take(NB * 4);
  a.W1aP = (u16 *)take(3072UL * 1024 * 2);
  a.W1vP = (u16 *)take(3072UL * 2048 * 2);
  a.W1cP = (u16 *)take(3072UL * 1024 * 2);
  a.Whh1P = (u16 *)take(3072UL * 1024 * 2);
  a.Whh2P = (u16 *)take(3072UL * 1024 * 2);
  a.Wih2aP = (u16 *)take(3072UL * 2048 * 2);
  a.W2P = (u16 *)take((size_t)NTOK * 1024 * 2);
  a.Wq1P = (u16 *)take(1024UL * 1024 * 2);
  a.Wih2qP = (u16 *)take(3072UL * 1024 * 2);
  a.capphp = (u16 *)take(19UL * 8 * 32 * 512 * 2);
  a.capplp = (u16 *)take(19UL * 8 * 32 * 512 * 2);
  a.Wvh = (u16 *)take(1024UL * 2048 * 2);
  a.vh = (u16 *)take((size_t)NB * NOBJ * VDIM * 2);
  a.Wqh = (u16 *)take(1024UL * 1024 * 2);
  a.Wql = (u16 *)take(1024UL * 1024 * 2);
  a.W1T = (u16 *)take(1024UL * 1024 * 2);
  a.Wih2c = (u16 *)take(3072UL * 1024 * 2);
  a.Wih2hql = (u16 *)take(3072UL * 1024 * 2);
  a.vproj16 = (u16 *)take((size_t)NB * NOBJ * HID * 2);
  a.h1hp = (u16 *)take(2UL * 8 * 32 * 512 * 2);
  a.h1lp = (u16 *)take(2UL * 8 * 32 * 512 * 2);
  a.h2hp = (u16 *)take(2UL * 8 * 32 * 512 * 2);
  a.h2lp = (u16 *)take(2UL * 8 * 32 * 512 * 2);
  a.avhp = (u16 *)take(8UL * 64 * 512 * 2);
  a.avlp = (u16 *)take(8UL * 64 * 512 * 2);
  a.vmhp = (u16 *)take(8UL * 64 * 512 * 2);
  a.vmlp = (u16 *)take(8UL * 64 * 512 * 2);
  a.gv1 = (float *)take((size_t)NB * 3072 * 4);
  a.gh2s = (float *)take((size_t)NB * 3072 * 4);
  a.h1f = (float *)take((size_t)2 * HSZ * 4);
  a.h2f = (float *)take((size_t)2 * HSZ * 4);
  a.qf = (float *)take((size_t)HSZ * 4);
  a.gcap = (float *)take((size_t)T_STEPS * NB * 3072 * 4);
  a.g1c = (float *)take((size_t)NB * 3072 * 4);
  a.gi2h1 = (float *)take((size_t)NB * 3072 * 4);
  a.bq1f = (float *)take(1024UL * 4);
  a.bf2f = (float *)take(3072UL * 4);

  static int gridBlocks = 0;
  if (gridBlocks == 0) {
    int occ = 0;
    if (hipOccupancyMaxActiveBlocksPerMultiprocessor(&occ, (const void *)butd,
                                                     512, 0) != hipSuccess ||
        occ < 1)
      occ = 1;
    gridBlocks = (occ >= 2) ? 512 : 256;
  }

  (void)hipMemsetAsync((void *)a.bar, 0, BAR_BYTES, stream);
  void *kargs[] = {(void *)&a};
  hipLaunchCooperativeKernel((const void *)butd, dim3(gridBlocks), dim3(512),
                             kargs, 0, stream);
}